// Round 6
// baseline (1206.550 us; speedup 1.0000x reference)
//
#include <hip/hip_runtime.h>
#include <math.h>

typedef unsigned short ushort;
typedef unsigned int uint;
typedef __bf16 bf16x8 __attribute__((ext_vector_type(8)));
typedef float f32x4 __attribute__((ext_vector_type(4)));

// Problem constants
#define ZS    128
#define KS    256
#define HS    512
#define BATCH 512
#define TT    32
#define MM    33
#define NB    2304      // 2048 gate cols (n = j*4+gate) + 256 key cols
#define KPAD  800       // 0..256 key_r, 257..271 zero pad, 272..783 h, 784..799 pad
#define HOFF  272
#define LDA   800

static __device__ __forceinline__ float sigf(float x) { return 1.f / (1.f + expf(-x)); }
static __device__ __forceinline__ float bf2f(ushort u) { return __uint_as_float((uint)u << 16); }

// ---------------------------------------------------------------------------
// Weight prep: Whi/Wlo [2304][800] bf16 (n-major, k-contig); Behi/Belo
// [128][1024] from W_enc transposed; biasN fused.
// ---------------------------------------------------------------------------
__global__ void prep_w(const float* __restrict__ W_ih, const float* __restrict__ W_hh,
                       const float* __restrict__ W_key, const float* __restrict__ b_ih,
                       const float* __restrict__ b_hh, const float* __restrict__ b_key,
                       const float* __restrict__ W_enc,
                       ushort* __restrict__ Whi, ushort* __restrict__ Wlo,
                       ushort* __restrict__ Behi, ushort* __restrict__ Belo,
                       float* __restrict__ biasN)
{
    int idx = blockIdx.x * 256 + threadIdx.x;
    if (idx < NB) {
        float bv;
        if (idx < 2048) { int j = idx >> 2, gi = idx & 3, r = gi * 512 + j; bv = b_ih[r] + b_hh[r]; }
        else bv = b_key[idx - 2048];
        biasN[idx] = bv;
    }
    if (idx < NB * KPAD) {
        int n = idx / KPAD, k = idx - n * KPAD;
        float v = 0.f;
        if (n < 2048) {
            int j = n >> 2, gi = n & 3, r = gi * 512 + j;
            if (k < 257) v = W_ih[r * 257 + k];
            else if (k >= HOFF && k < HOFF + 512) v = W_hh[r * 512 + (k - HOFF)];
        } else {
            if (k >= HOFF && k < HOFF + 512) v = W_key[(n - 2048) * 512 + (k - HOFF)];
        }
        uint u = __float_as_uint(v);
        Whi[idx] = (ushort)(u >> 16);
        float lo = v - __uint_as_float(u & 0xFFFF0000u);
        Wlo[idx] = (ushort)(__float_as_uint(lo) >> 16);
    } else if (idx < NB * KPAD + 128 * 1024) {
        int e = idx - NB * KPAD;
        int n = e >> 10, k = e & 1023;
        float v = W_enc[k * 128 + n];
        uint u = __float_as_uint(v);
        Behi[e] = (ushort)(u >> 16);
        float lo = v - __uint_as_float(u & 0xFFFF0000u);
        Belo[e] = (ushort)(__float_as_uint(lo) >> 16);
    }
}

// ---------------------------------------------------------------------------
// bf16x3 MFMA GEMM, plain-__syncthreads double-buffered window loop.
// NCH = 32-k chunks per window (NCH=2 -> BK=64: half the barriers, 2x MFMA
// per window vs NCH=1). Window w reads buf[w&1]; loads for window w+1 are
// issued right AFTER the barrier (so L2 latency hides under COMPUTE before
// STORE's counted vmcnt wait); STORE writes buf[(w+1)&1]. One __syncthreads
// per window; no inline-asm barriers (round-5 race post-mortem).
//  * MODE 1: flat grid 576 with XCD-contiguous bx swizzle (weights ~1 MB/XCD,
//    L2-resident across all 33 steps).
//  * MODE 0: K-split via blockIdx.z (2 halves of 512); half 1 -> Mk scratch,
//    reduced in norm_k.
// ---------------------------------------------------------------------------
#define LOADC_M(s, avf_, avu_, bhv_, blv_) do {                                   \
    const int k0 = (s) * 32;                                                      \
    if (PRESPLIT) {                                                               \
        int idx = tid & 127, r = idx >> 2, c = (idx & 3) << 3;                    \
        const ushort* srcp = (tid < 128) ? Ahi : Alo;                             \
        avu_ = *(const uint4*)(srcp + (size_t)(row0 + r) * lda + k0 + c);         \
    } else {                                                                      \
        int r = tid >> 3, c = (tid & 7) << 2;                                     \
        avf_ = *(const float4*)(A + (size_t)(row0 + r) * lda + k0 + c);           \
    }                                                                             \
    _Pragma("unroll")                                                             \
    for (int i = 0; i < BN / 64; i++) {                                           \
        int idx2 = tid + 256 * i, r2 = idx2 >> 2, c2 = (idx2 & 3) << 3;           \
        bhv_[i] = *(const uint4*)(Bhi + (size_t)(n0 + r2) * ldb + k0 + c2);       \
        blv_[i] = *(const uint4*)(Blo + (size_t)(n0 + r2) * ldb + k0 + c2);       \
    }                                                                             \
} while (0)

#define STOREC_M(wb, ch, avf_, avu_, bhv_, blv_) do {                             \
    ushort* Lw = lds + ((wb) * NCH + (ch)) * BUF_C;                               \
    if (PRESPLIT) {                                                               \
        int idx = tid & 127, r = idx >> 2, c = (idx & 3) << 3;                    \
        *(uint4*)&Lw[(tid < 128 ? AHI : ALO) + r * 40 + c] = avu_;                \
    } else {                                                                      \
        int r = tid >> 3, c = (tid & 7) << 2;                                     \
        uint u0 = __float_as_uint(avf_.x), u1 = __float_as_uint(avf_.y);          \
        uint u2 = __float_as_uint(avf_.z), u3 = __float_as_uint(avf_.w);          \
        uint hp0 = (u1 & 0xFFFF0000u) | (u0 >> 16);                               \
        uint hp1 = (u3 & 0xFFFF0000u) | (u2 >> 16);                               \
        float l0 = avf_.x - __uint_as_float(u0 & 0xFFFF0000u);                    \
        float l1 = avf_.y - __uint_as_float(u1 & 0xFFFF0000u);                    \
        float l2 = avf_.z - __uint_as_float(u2 & 0xFFFF0000u);                    \
        float l3 = avf_.w - __uint_as_float(u3 & 0xFFFF0000u);                    \
        uint lp0 = (__float_as_uint(l1) & 0xFFFF0000u) | (__float_as_uint(l0) >> 16); \
        uint lp1 = (__float_as_uint(l3) & 0xFFFF0000u) | (__float_as_uint(l2) >> 16); \
        *(uint2*)&Lw[AHI + r * 40 + c] = make_uint2(hp0, hp1);                    \
        *(uint2*)&Lw[ALO + r * 40 + c] = make_uint2(lp0, lp1);                    \
    }                                                                             \
    _Pragma("unroll")                                                             \
    for (int i = 0; i < BN / 64; i++) {                                           \
        int idx3 = tid + 256 * i, r3 = idx3 >> 2, c3 = (idx3 & 3) << 3;           \
        *(uint4*)&Lw[BHI + r3 * 40 + c3] = bhv_[i];                               \
        *(uint4*)&Lw[BLO + r3 * 40 + c3] = blv_[i];                               \
    }                                                                             \
} while (0)

template<int BN, int MODE, bool PRESPLIT, int NCH>
__global__ __launch_bounds__(256, 4)
void gemm_mfma(const float* __restrict__ A,
               const ushort* __restrict__ Ahi, const ushort* __restrict__ Alo, int lda,
               const ushort* __restrict__ Bhi, const ushort* __restrict__ Blo, int ldb,
               int nslice,
               float* __restrict__ out,              // MODE0: z_pad (half-0 partial)
               ushort* __restrict__ outHi, ushort* __restrict__ outLo,  // MODE1: next input
               const float* __restrict__ biasN,
               float* __restrict__ cst, float* __restrict__ Mk, int step)
{
    constexpr int NI = BN / 32;            // N subtiles per wave
    constexpr int AHI = 0, ALO = 32 * 40, BHI = 64 * 40, BLO = 64 * 40 + BN * 40;
    constexpr int BUF_C = 64 * 40 + 2 * BN * 40;   // ushorts per 32-k chunk
    __shared__ ushort lds[2 * NCH * BUF_C];

    const int tid = threadIdx.x;
    int bx, by;
    if (MODE == 1) {
        int wg = blockIdx.x;
        int swz = (wg & 7) * 72 + (wg >> 3);   // 576 = 8 XCDs * 72, bijective
        bx = swz >> 4; by = swz & 15;
    } else {
        bx = blockIdx.x; by = blockIdx.y;
        A   += (size_t)blockIdx.z * 512;
        Bhi += (size_t)blockIdx.z * 512;
        Blo += (size_t)blockIdx.z * 512;
        if (blockIdx.z) out = Mk;   // half-1 partial -> Mk scratch (read by norm_k)
    }
    const int row0 = by * 32, n0 = bx * BN;
    const int l = tid & 63, w = tid >> 6, wm = w >> 1, wn = w & 1;
    const int lm = l & 15, kg = (l >> 4) << 3;

    f32x4 acc[NI];
    const f32x4 zero4 = {0.f, 0.f, 0.f, 0.f};
#pragma unroll
    for (int ni = 0; ni < NI; ni++) acc[ni] = zero4;

    // one register set per chunk (static names, short lifetime within window)
    float4 avf0, avf1;
    uint4 avu0, avu1;
    uint4 bhv0[BN / 64], blv0[BN / 64], bhv1[BN / 64], blv1[BN / 64];

    auto COMPUTE = [&](int wb, int ch) {
        const ushort* L = lds + (wb * NCH + ch) * BUF_C;
        bf16x8 ah, alv, bh[NI], bl[NI];
        {
            int r = wm * 16 + lm;
            ah  = *(const bf16x8*)&L[AHI + r * 40 + kg];
            alv = *(const bf16x8*)&L[ALO + r * 40 + kg];
        }
#pragma unroll
        for (int ni = 0; ni < NI; ni++) {
            int r = wn * (BN / 2) + ni * 16 + lm;
            bh[ni] = *(const bf16x8*)&L[BHI + r * 40 + kg];
            bl[ni] = *(const bf16x8*)&L[BLO + r * 40 + kg];
        }
#pragma unroll
        for (int ni = 0; ni < NI; ni++) {
            acc[ni] = __builtin_amdgcn_mfma_f32_16x16x32_bf16(ah,  bh[ni], acc[ni], 0, 0, 0);
            acc[ni] = __builtin_amdgcn_mfma_f32_16x16x32_bf16(ah,  bl[ni], acc[ni], 0, 0, 0);
            acc[ni] = __builtin_amdgcn_mfma_f32_16x16x32_bf16(alv, bh[ni], acc[ni], 0, 0, 0);
        }
    };

    // prologue: window 0 -> buf 0
    LOADC_M(0, avf0, avu0, bhv0, blv0);
    if (NCH == 2 && 1 < nslice) LOADC_M(1, avf1, avu1, bhv1, blv1);
    STOREC_M(0, 0, avf0, avu0, bhv0, blv0);
    if (NCH == 2 && 1 < nslice) STOREC_M(0, 1, avf1, avu1, bhv1, blv1);

    const int nwin = (nslice + NCH - 1) / NCH;
    for (int wi = 0; wi < nwin; wi++) {
        __syncthreads();                       // buf[wi&1] visible to all waves
        const int nb = (wi + 1) * NCH;         // first slice of next window
        if (nb < nslice) LOADC_M(nb, avf0, avu0, bhv0, blv0);
        if (NCH == 2 && nb + 1 < nslice) LOADC_M(nb + 1, avf1, avu1, bhv1, blv1);
        COMPUTE(wi & 1, 0);
        if (NCH == 2 && wi * NCH + 1 < nslice) COMPUTE(wi & 1, 1);
        if (nb < nslice) {
            STOREC_M((wi + 1) & 1, 0, avf0, avu0, bhv0, blv0);
            if (NCH == 2 && nb + 1 < nslice) STOREC_M((wi + 1) & 1, 1, avf1, avu1, bhv1, blv1);
        }
    }

    const int crow = (l >> 4) << 2;   // C/D: row = (lane>>4)*4 + reg, col = lane&15
    if (MODE == 0) {
#pragma unroll
        for (int ni = 0; ni < NI; ni++)
#pragma unroll
            for (int r = 0; r < 4; r++) {
                int m = row0 + wm * 16 + crow + r;
                int z = n0 + wn * (BN / 2) + ni * 16 + lm;
                out[(size_t)(m >> 5) * (MM * ZS) + (m & 31) * ZS + z] = acc[ni][r];
            }
    } else if (bx < 32) {
        // gate cols: per-wave LDS exchange so one thread owns i,f,g,o of a unit
        __syncthreads();
        float* epi = (float*)lds;
        float* ew = epi + w * 544;           // 16 rows x 34 stride per wave
#pragma unroll
        for (int ni = 0; ni < NI; ni++)
#pragma unroll
            for (int r = 0; r < 4; r++) {
                int ml = crow + r, nl = ni * 16 + lm;
                ew[ml * 34 + nl] = acc[ni][r] + biasN[n0 + wn * 32 + nl];
            }
        __syncthreads();
        int row = tid >> 3, jj8 = tid & 7;   // row 0..31, j-pair 0..7
        int b = row0 + row;
        int j0 = bx * 16 + jj8 * 2;
        float2 cold = *(float2*)&cst[(size_t)b * HS + j0];
        float cc[2] = {cold.x, cold.y}, hv[2];
#pragma unroll
        for (int i = 0; i < 2; i++) {
            int jj = jj8 * 2 + i;
            float p[4];
#pragma unroll
            for (int g = 0; g < 4; g++) {
                int n = jj * 4 + g;
                int wv = (row >> 4) * 2 + (n >> 5);
                p[g] = epi[wv * 544 + (row & 15) * 34 + (n & 31)];
            }
            float ig = sigf(p[0]), fg = sigf(p[1]), gg = tanhf(p[2]), og = sigf(p[3]);
            float cn = fg * cc[i] + ig * gg;
            hv[i] = og * tanhf(cn);
            cc[i] = cn;
        }
        *(float2*)&cst[(size_t)b * HS + j0] = make_float2(cc[0], cc[1]);
        // write h pre-split bf16 hi/lo into next-step input
        uint u0 = __float_as_uint(hv[0]), u1 = __float_as_uint(hv[1]);
        uint hp = (u1 & 0xFFFF0000u) | (u0 >> 16);
        float l0 = hv[0] - __uint_as_float(u0 & 0xFFFF0000u);
        float l1 = hv[1] - __uint_as_float(u1 & 0xFFFF0000u);
        uint lp = (__float_as_uint(l1) & 0xFFFF0000u) | (__float_as_uint(l0) >> 16);
        *(uint*)&outHi[(size_t)b * LDA + HOFF + j0] = hp;
        *(uint*)&outLo[(size_t)b * LDA + HOFF + j0] = lp;
    } else if (step >= 1) {
        // key cols: relu -> Mk slot step-1
#pragma unroll
        for (int ni = 0; ni < NI; ni++)
#pragma unroll
            for (int r = 0; r < 4; r++) {
                int b = row0 + wm * 16 + crow + r;
                int cg = n0 + wn * 32 + ni * 16 + lm;
                float v = fmaxf(acc[ni][r] + biasN[cg], 0.f);
                Mk[((size_t)(step - 1) * BATCH + b) * KS + (cg - 2048)] = v;
            }
    }
}

#undef LOADC_M
#undef STOREC_M

// ---------------------------------------------------------------------------
// Context norm over T. Sums the two K-split encoder partials (z2 aliases the
// Mk buffer, which is unused until step 1), then normalizes in place and
// writes zero row t=32.
// ---------------------------------------------------------------------------
__global__ void norm_k(float* __restrict__ z_pad, const float* __restrict__ z2,
                       const float* __restrict__ gamma, const float* __restrict__ beta)
{
    int b = blockIdx.x, zc = threadIdx.x;
    float* zb = z_pad + (size_t)b * (MM * ZS);
    const float* zb2 = z2 + (size_t)b * (MM * ZS);
    float s = 0.f, s2 = 0.f;
    for (int t = 0; t < TT; t++) {
        float v = zb[t * ZS + zc] + zb2[t * ZS + zc];
        zb[t * ZS + zc] = v;
        s += v; s2 += v * v;
    }
    float mu = s * (1.f / 32.f);
    float var = s2 * (1.f / 32.f) - mu * mu;
    float rstd = 1.f / sqrtf(var + 1e-8f);
    float ga = gamma[zc], be = beta[zc];
    for (int t = 0; t < TT; t++) {
        float v = zb[t * ZS + zc];
        zb[t * ZS + zc] = (v - mu) * rstd * ga + be;
    }
    zb[TT * ZS + zc] = 0.f;
}

// ---------------------------------------------------------------------------
// Precompute attention weights + confidence sums (z-only, loop-invariant).
// ---------------------------------------------------------------------------
__global__ __launch_bounds__(256)
void scores_k(const float* __restrict__ z_pad, const float* __restrict__ cg_p,
              const float* __restrict__ cb_p, float* __restrict__ watt,
              float* __restrict__ wc)
{
    __shared__ float zs[MM * 129];
    int b = blockIdx.x, tid = threadIdx.x;
    const float* zb = z_pad + (size_t)b * (MM * ZS);
    for (int i = tid; i < MM * ZS; i += 256) {
        int m = i >> 7, k = i & 127;
        zs[m * 129 + k] = zb[i];
    }
    __syncthreads();
    float cg = cg_p[0], cb = cb_p[0];
    int wid = tid >> 6, lane = tid & 63;
    for (int t = 1 + wid; t <= 32; t += 4) {
        int m = lane;
        float s = -3.0e38f;
        if (m < t) {
            const float* zt = &zs[t * 129];
            const float* zm = &zs[m * 129];
            float acc = 0.f;
#pragma unroll 8
            for (int k = 0; k < ZS; k++) acc += zt[k] * zm[k];
            s = acc;
        }
        float mx = s;
        for (int off = 1; off < 64; off <<= 1) mx = fmaxf(mx, __shfl_xor(mx, off));
        float e = (m < t) ? expf(s - mx) : 0.f;
        float sum = e;
        for (int off = 1; off < 64; off <<= 1) sum += __shfl_xor(sum, off);
        float w = e / sum;
        if (m < t) watt[(b * MM + t) * MM + m] = w;
        float p = (m < t) ? w * sigf(s * cg + cb) : 0.f;
        for (int off = 1; off < 64; off <<= 1) p += __shfl_xor(p, off);
        if (lane == 0) wc[b * MM + t] = p;
    }
}

// ---------------------------------------------------------------------------
// Post-step: g gate + attention read -> key_r(t+1) (bf16 hi/lo) into the
// same ping-pong buffer (disjoint cols vs h).
// ---------------------------------------------------------------------------
__global__ __launch_bounds__(256)
void post_k(ushort* __restrict__ inpHi, ushort* __restrict__ inpLo,
            const float* __restrict__ W_g, const float* __restrict__ b_g,
            const float* __restrict__ watt, const float* __restrict__ wc,
            const float* __restrict__ Mk, int t)
{
    __shared__ float red[256];
    __shared__ float wts[32];
    __shared__ float gsh;
    int b = blockIdx.x, tid = threadIdx.x;
    ushort* rHi = inpHi + (size_t)b * LDA;
    ushort* rLo = inpLo + (size_t)b * LDA;
    float h1 = bf2f(rHi[HOFF + tid]) + bf2f(rLo[HOFF + tid]);
    float h2 = bf2f(rHi[HOFF + 256 + tid]) + bf2f(rLo[HOFF + 256 + tid]);
    red[tid] = h1 * W_g[tid] + h2 * W_g[tid + 256];
    if (tid < t) wts[tid] = watt[(b * MM + t) * MM + tid];
    __syncthreads();
    for (int s = 128; s > 0; s >>= 1) {
        if (tid < s) red[tid] += red[tid + s];
        __syncthreads();
    }
    if (tid == 0) gsh = sigf(red[0] + b_g[0]);
    __syncthreads();
    float g = gsh;
    float acc = 0.f;
    for (int m = 0; m < t; m++)
        acc += wts[m] * Mk[((size_t)m * BATCH + b) * KS + tid];
    float v = g * acc;
    uint u = __float_as_uint(v);
    rHi[tid] = (ushort)(u >> 16);
    float lo = v - __uint_as_float(u & 0xFFFF0000u);
    rLo[tid] = (ushort)(__float_as_uint(lo) >> 16);
    if (tid == 0) {
        float vc = g * wc[b * MM + t];
        uint uc = __float_as_uint(vc);
        rHi[256] = (ushort)(uc >> 16);
        float lc = vc - __uint_as_float(uc & 0xFFFF0000u);
        rLo[256] = (ushort)(__float_as_uint(lc) >> 16);
    }
}

// ---------------------------------------------------------------------------
// Final y + argmax.
// ---------------------------------------------------------------------------
__global__ void y_k(const ushort* __restrict__ inpHi, const ushort* __restrict__ inpLo,
                    const float* __restrict__ W_y, const float* __restrict__ b_y,
                    float* __restrict__ out)
{
    int b = blockIdx.x, lane = threadIdx.x;
    const ushort* hHi = inpHi + (size_t)b * LDA + HOFF;
    const ushort* hLo = inpLo + (size_t)b * LDA + HOFF;
    float a0 = 0, a1 = 0, a2 = 0, a3 = 0;
    for (int r = 0; r < 8; r++) {
        int k = lane + r * 64;
        float hv = bf2f(hHi[k]) + bf2f(hLo[k]);
        a0 += hv * W_y[k];
        a1 += hv * W_y[512 + k];
        a2 += hv * W_y[1024 + k];
        a3 += hv * W_y[1536 + k];
    }
    for (int off = 32; off > 0; off >>= 1) {
        a0 += __shfl_xor(a0, off);
        a1 += __shfl_xor(a1, off);
        a2 += __shfl_xor(a2, off);
        a3 += __shfl_xor(a3, off);
    }
    if (lane == 0) {
        float y0 = a0 + b_y[0], y1 = a1 + b_y[1], y2 = a2 + b_y[2], y3 = a3 + b_y[3];
        out[b * 4 + 0] = y0; out[b * 4 + 1] = y1; out[b * 4 + 2] = y2; out[b * 4 + 3] = y3;
        int best = 0; float bv = y0;
        if (y1 > bv) { bv = y1; best = 1; }
        if (y2 > bv) { bv = y2; best = 2; }
        if (y3 > bv) { bv = y3; best = 3; }
        out[2048 + b] = (float)best;
    }
}

// ---------------------------------------------------------------------------
extern "C" void kernel_launch(void* const* d_in, const int* in_sizes, int n_in,
                              void* d_out, int out_size, void* d_ws, size_t ws_size,
                              hipStream_t stream)
{
    const float* x_seq = (const float*)d_in[0];
    const float* W_enc = (const float*)d_in[1];
    const float* gamma = (const float*)d_in[2];
    const float* beta  = (const float*)d_in[3];
    const float* W_ih  = (const float*)d_in[4];
    const float* W_hh  = (const float*)d_in[5];
    const float* b_ih  = (const float*)d_in[6];
    const float* b_hh  = (const float*)d_in[7];
    const float* W_key = (const float*)d_in[8];
    const float* b_key = (const float*)d_in[9];
    const float* W_g   = (const float*)d_in[10];
    const float* b_g   = (const float*)d_in[11];
    const float* cgain = (const float*)d_in[12];
    const float* cbias = (const float*)d_in[13];
    const float* W_y   = (const float*)d_in[14];
    const float* b_y   = (const float*)d_in[15];

    float* ws    = (float*)d_ws;
    float* z_pad = ws;                          // 2,162,688 f
    float* watt  = z_pad + 2162688;             // 557,568 f
    float* wcv   = watt + 557568;               // 16,896 f
    float* Mk    = wcv + 16896;                 // 4,194,304 f (doubles as z half-1 partial pre-loop)
    float* biasN = Mk + 4194304;                // 2,304 f
    float* cst   = biasN + 2304;                // 262,144 f
    ushort* inpHi0 = (ushort*)(cst + 262144);   // 409,600 us each
    ushort* inpLo0 = inpHi0 + 409600;
    ushort* inpHi1 = inpLo0 + 409600;
    ushort* inpLo1 = inpHi1 + 409600;
    ushort* Whi  = inpLo1 + 409600;             // 1,843,200 us
    ushort* Wlo  = Whi + NB * KPAD;             // 1,843,200 us
    ushort* Behi = Wlo + NB * KPAD;             // 131,072 us
    ushort* Belo = Behi + 131072;               // 131,072 us

    // zero c-state + all 4 input ping-pong buffers (contiguous region)
    hipMemsetAsync(cst, 0, 262144 * sizeof(float) + 4 * 409600 * sizeof(ushort), stream);

    prep_w<<<(NB * KPAD + 131072 + 255) / 256, 256, 0, stream>>>(
        W_ih, W_hh, W_key, b_ih, b_hh, b_key, W_enc, Whi, Wlo, Behi, Belo, biasN);

    // encoder: [16384 x 1024] @ [1024 x 128] -> z_pad, K split in 2 halves
    // (half 0 -> z_pad, half 1 -> Mk scratch; reduced in norm_k)
    gemm_mfma<128, 0, false, 1><<<dim3(1, 512, 2), 256, 0, stream>>>(
        x_seq, nullptr, nullptr, 1024, Behi, Belo, 1024, 16,
        z_pad, nullptr, nullptr, nullptr, nullptr, Mk, 0);
    norm_k<<<512, 128, 0, stream>>>(z_pad, Mk, gamma, beta);
    scores_k<<<512, 256, 0, stream>>>(z_pad, cgain, cbias, watt, wcv);

    for (int t = 0; t <= 32; t++) {
        ushort* inHiC = (t & 1) ? inpHi1 : inpHi0;
        ushort* inLoC = (t & 1) ? inpLo1 : inpLo0;
        ushort* inHiN = (t & 1) ? inpHi0 : inpHi1;
        ushort* inLoN = (t & 1) ? inpLo0 : inpLo1;
        gemm_mfma<64, 1, true, 2><<<dim3(576), 256, 0, stream>>>(
            nullptr, inHiC, inLoC, LDA, Whi, Wlo, KPAD, 25,
            nullptr, inHiN, inLoN, biasN, cst, Mk, t);
        if (t >= 1 && t <= 31)
            post_k<<<512, 256, 0, stream>>>(inHiN, inLoN, W_g, b_g, watt, wcv, Mk, t);
    }
    y_k<<<512, 64, 0, stream>>>((0 ? inpHi0 : inpHi1), (0 ? inpLo0 : inpLo1),
                                W_y, b_y, (float*)d_out);
}

// Round 8
// 1011.155 us; speedup vs baseline: 1.1932x; 1.1932x over previous
//
#include <hip/hip_runtime.h>
#include <math.h>

typedef unsigned short ushort;
typedef unsigned int uint;
typedef __bf16 bf16x8 __attribute__((ext_vector_type(8)));
typedef float f32x4 __attribute__((ext_vector_type(4)));

// Problem constants
#define ZS    128
#define KS    256
#define HS    512
#define BATCH 512
#define TT    32
#define MM    33
#define NB    2304      // 2048 gate cols (n = j*4+gate) + 256 key cols
#define KPAD  800       // 0..256 key_r, 257..271 zero pad, 272..783 h, 784..799 pad
#define HOFF  272
#define LDA   800

static __device__ __forceinline__ float sigf(float x) { return 1.f / (1.f + expf(-x)); }
static __device__ __forceinline__ float bf2f(ushort u) { return __uint_as_float((uint)u << 16); }

// ---------------------------------------------------------------------------
// Weight prep: Whi/Wlo [2304][800] bf16 (n-major, k-contig); Behi/Belo
// [128][1024] from W_enc transposed; biasN fused.
// ---------------------------------------------------------------------------
__global__ void prep_w(const float* __restrict__ W_ih, const float* __restrict__ W_hh,
                       const float* __restrict__ W_key, const float* __restrict__ b_ih,
                       const float* __restrict__ b_hh, const float* __restrict__ b_key,
                       const float* __restrict__ W_enc,
                       ushort* __restrict__ Whi, ushort* __restrict__ Wlo,
                       ushort* __restrict__ Behi, ushort* __restrict__ Belo,
                       float* __restrict__ biasN)
{
    int idx = blockIdx.x * 256 + threadIdx.x;
    if (idx < NB) {
        float bv;
        if (idx < 2048) { int j = idx >> 2, gi = idx & 3, r = gi * 512 + j; bv = b_ih[r] + b_hh[r]; }
        else bv = b_key[idx - 2048];
        biasN[idx] = bv;
    }
    if (idx < NB * KPAD) {
        int n = idx / KPAD, k = idx - n * KPAD;
        float v = 0.f;
        if (n < 2048) {
            int j = n >> 2, gi = n & 3, r = gi * 512 + j;
            if (k < 257) v = W_ih[r * 257 + k];
            else if (k >= HOFF && k < HOFF + 512) v = W_hh[r * 512 + (k - HOFF)];
        } else {
            if (k >= HOFF && k < HOFF + 512) v = W_key[(n - 2048) * 512 + (k - HOFF)];
        }
        uint u = __float_as_uint(v);
        Whi[idx] = (ushort)(u >> 16);
        float lo = v - __uint_as_float(u & 0xFFFF0000u);
        Wlo[idx] = (ushort)(__float_as_uint(lo) >> 16);
    } else if (idx < NB * KPAD + 128 * 1024) {
        int e = idx - NB * KPAD;
        int n = e >> 10, k = e & 1023;
        float v = W_enc[k * 128 + n];
        uint u = __float_as_uint(v);
        Behi[e] = (ushort)(u >> 16);
        float lo = v - __uint_as_float(u & 0xFFFF0000u);
        Belo[e] = (ushort)(__float_as_uint(lo) >> 16);
    }
}

// ---------------------------------------------------------------------------
// bf16x3 MFMA GEMM — exact R0 loop structure (proven 1015 us baseline):
//   LOADG(0); STORE(0); for s { LOADG(s+1); __syncthreads; COMPUTE(s); STORE(s+1); }
//  * MODE 0 (encoder): grid (1,512), nslice=32, writes z_pad. Unchanged vs R0.
//  * MODE 1 (step): K-SPLIT z=2 (slices 0..12 / 13..24) -> flat grid 1152
//    (= 8 XCDs x 144, XCD-contiguous swizzle; z=0 on XCDs 0-3, z=1 on 4-7;
//    each XCD owns 9 contiguous bx tiles ~1 MB weights, L2-resident).
//    4.5 blocks/CU (vs 2.25 before) — occupancy was the binding constraint
//    (R6 post-mortem). Writes RAW fp32 partials to P0/P1; bias + LSTM cell +
//    key relu + attention all moved to cell_k.
// ---------------------------------------------------------------------------
template<int BN, int MODE, bool PRESPLIT>
__global__ __launch_bounds__(256, (MODE == 1) ? 5 : 4)
void gemm_mfma(const float* __restrict__ A,
               const ushort* __restrict__ Ahi, const ushort* __restrict__ Alo, int lda,
               const ushort* __restrict__ Bhi, const ushort* __restrict__ Blo, int ldb,
               int nslice,
               float* __restrict__ out,   // MODE0: z_pad; MODE1: P0 (z=0 partial)
               float* __restrict__ out2)  // MODE1: P1 (z=1 partial)
{
    constexpr int NI = BN / 32;            // N subtiles per wave
    constexpr int AHI = 0, ALO = 32 * 40, BHI = 64 * 40, BLO = 64 * 40 + BN * 40;
    constexpr int BUF = 64 * 40 + 2 * BN * 40;   // ushorts per stage buffer
    __shared__ ushort lds[2 * BUF];

    const int tid = threadIdx.x;
    int bx, by, kb, kc;
    if (MODE == 1) {
        int wg = blockIdx.x;
        int swz = (wg & 7) * 144 + (wg >> 3);   // 1152 = 8 XCDs * 144, bijective
        int zz = swz / 576;
        int r  = swz - zz * 576;
        bx = r >> 4; by = r & 15;
        kb = zz ? 13 : 0;                       // slice base
        kc = zz ? 12 : 13;                      // slice count (total 25)
        if (zz) out = out2;
    } else {
        bx = blockIdx.x; by = blockIdx.y;
        kb = 0; kc = nslice;
    }
    const int row0 = by * 32, n0 = bx * BN;
    const int l = tid & 63, w = tid >> 6, wm = w >> 1, wn = w & 1;
    const int lm = l & 15, kg = (l >> 4) << 3;

    f32x4 acc[NI];
    const f32x4 zero4 = {0.f, 0.f, 0.f, 0.f};
#pragma unroll
    for (int ni = 0; ni < NI; ni++) acc[ni] = zero4;

    float4 avf;
    uint4 avu;
    uint4 bhv[BN / 64], blv[BN / 64];

    auto LOADG = [&](int a) {           // a = absolute slice index
        const int k0 = a * 32;
        if (PRESPLIT) {
            int idx = tid & 127, r = idx >> 2, c = (idx & 3) << 3;
            const ushort* src = (tid < 128) ? Ahi : Alo;
            avu = *(const uint4*)(src + (size_t)(row0 + r) * lda + k0 + c);
        } else {
            int r = tid >> 3, c = (tid & 7) << 2;
            avf = *(const float4*)(A + (size_t)(row0 + r) * lda + k0 + c);
        }
#pragma unroll
        for (int i = 0; i < BN / 64; i++) {
            int idx = tid + 256 * i, r = idx >> 2, c = (idx & 3) << 3;
            bhv[i] = *(const uint4*)(Bhi + (size_t)(n0 + r) * ldb + k0 + c);
            blv[i] = *(const uint4*)(Blo + (size_t)(n0 + r) * ldb + k0 + c);
        }
    };
    auto STORE = [&](int buf) {
        ushort* L = lds + buf * BUF;
        if (PRESPLIT) {
            int idx = tid & 127, r = idx >> 2, c = (idx & 3) << 3;
            *(uint4*)&L[(tid < 128 ? AHI : ALO) + r * 40 + c] = avu;
        } else {
            int r = tid >> 3, c = (tid & 7) << 2;
            uint u0 = __float_as_uint(avf.x), u1 = __float_as_uint(avf.y);
            uint u2 = __float_as_uint(avf.z), u3 = __float_as_uint(avf.w);
            uint hp0 = (u1 & 0xFFFF0000u) | (u0 >> 16);
            uint hp1 = (u3 & 0xFFFF0000u) | (u2 >> 16);
            float l0 = avf.x - __uint_as_float(u0 & 0xFFFF0000u);
            float l1 = avf.y - __uint_as_float(u1 & 0xFFFF0000u);
            float l2 = avf.z - __uint_as_float(u2 & 0xFFFF0000u);
            float l3 = avf.w - __uint_as_float(u3 & 0xFFFF0000u);
            uint lp0 = (__float_as_uint(l1) & 0xFFFF0000u) | (__float_as_uint(l0) >> 16);
            uint lp1 = (__float_as_uint(l3) & 0xFFFF0000u) | (__float_as_uint(l2) >> 16);
            *(uint2*)&L[AHI + r * 40 + c] = make_uint2(hp0, hp1);
            *(uint2*)&L[ALO + r * 40 + c] = make_uint2(lp0, lp1);
        }
#pragma unroll
        for (int i = 0; i < BN / 64; i++) {
            int idx = tid + 256 * i, r = idx >> 2, c = (idx & 3) << 3;
            *(uint4*)&L[BHI + r * 40 + c] = bhv[i];
            *(uint4*)&L[BLO + r * 40 + c] = blv[i];
        }
    };
    auto COMPUTE = [&](int buf) {
        const ushort* L = lds + buf * BUF;
        bf16x8 ah, alv, bh[NI], bl[NI];
        {
            int r = wm * 16 + lm;
            ah  = *(const bf16x8*)&L[AHI + r * 40 + kg];
            alv = *(const bf16x8*)&L[ALO + r * 40 + kg];
        }
#pragma unroll
        for (int ni = 0; ni < NI; ni++) {
            int r = wn * (BN / 2) + ni * 16 + lm;
            bh[ni] = *(const bf16x8*)&L[BHI + r * 40 + kg];
            bl[ni] = *(const bf16x8*)&L[BLO + r * 40 + kg];
        }
#pragma unroll
        for (int ni = 0; ni < NI; ni++) {
            acc[ni] = __builtin_amdgcn_mfma_f32_16x16x32_bf16(ah,  bh[ni], acc[ni], 0, 0, 0);
            acc[ni] = __builtin_amdgcn_mfma_f32_16x16x32_bf16(ah,  bl[ni], acc[ni], 0, 0, 0);
            acc[ni] = __builtin_amdgcn_mfma_f32_16x16x32_bf16(alv, bh[ni], acc[ni], 0, 0, 0);
        }
    };

    LOADG(kb);
    STORE(0);
    for (int s = 0; s < kc; s++) {
        if (s + 1 < kc) LOADG(kb + s + 1);
        __syncthreads();
        COMPUTE(s & 1);
        if (s + 1 < kc) STORE((s + 1) & 1);
    }

    const int crow = (l >> 4) << 2;   // C/D: row = (lane>>4)*4 + reg, col = lane&15
    if (MODE == 0) {
#pragma unroll
        for (int ni = 0; ni < NI; ni++)
#pragma unroll
            for (int r = 0; r < 4; r++) {
                int m = row0 + wm * 16 + crow + r;
                int z = n0 + wn * (BN / 2) + ni * 16 + lm;
                out[(size_t)(m >> 5) * (MM * ZS) + (m & 31) * ZS + z] = acc[ni][r];
            }
    } else {
        // raw fp32 partial: P[b][n]
#pragma unroll
        for (int ni = 0; ni < NI; ni++)
#pragma unroll
            for (int r = 0; r < 4; r++) {
                int b = row0 + wm * 16 + crow + r;
                int n = n0 + wn * (BN / 2) + ni * 16 + lm;
                out[(size_t)b * NB + n] = acc[ni][r];
            }
    }
}

// ---------------------------------------------------------------------------
// Fused per-step cell: sums K-split partials, bias, LSTM cell, h write
// (bf16 hi/lo), key relu -> Mk, then g-gate + attention read -> key_r(t+1).
// Replaces the old GEMM epilogue AND post_k. One block per batch row.
// Mk row t-1 is consumed from the local register (kv), not re-read.
// ---------------------------------------------------------------------------
__global__ __launch_bounds__(256)
void cell_k(const float* __restrict__ P0, const float* __restrict__ P1,
            const float* __restrict__ biasN, float* __restrict__ cst,
            ushort* __restrict__ outHi, ushort* __restrict__ outLo,
            float* __restrict__ Mk,
            const float* __restrict__ W_g, const float* __restrict__ b_g,
            const float* __restrict__ watt, const float* __restrict__ wc,
            int t)
{
    __shared__ float hsh[512];
    __shared__ float red[256];
    __shared__ float wts[32];
    __shared__ float gsh;
    int b = blockIdx.x, tid = threadIdx.x;
    const float* p0 = P0 + (size_t)b * NB;
    const float* p1 = P1 + (size_t)b * NB;
    ushort* rHi = outHi + (size_t)b * LDA;
    ushort* rLo = outLo + (size_t)b * LDA;
#pragma unroll
    for (int u = 0; u < 2; u++) {
        int j = tid + u * 256;                 // hidden unit
        float4 a  = *(const float4*)(p0 + 4 * j);
        float4 c4 = *(const float4*)(p1 + 4 * j);
        float4 bb = *(const float4*)(biasN + 4 * j);
        float gi = a.x + c4.x + bb.x;          // PyTorch gate order i,f,g,o
        float gf = a.y + c4.y + bb.y;
        float gg = a.z + c4.z + bb.z;
        float go = a.w + c4.w + bb.w;
        float iv = sigf(gi), fv = sigf(gf), gv = tanhf(gg), ov = sigf(go);
        float cn = fv * cst[(size_t)b * HS + j] + iv * gv;
        float hv = ov * tanhf(cn);
        cst[(size_t)b * HS + j] = cn;
        hsh[j] = hv;
        uint uu = __float_as_uint(hv);
        rHi[HOFF + j] = (ushort)(uu >> 16);
        float lo = hv - __uint_as_float(uu & 0xFFFF0000u);
        rLo[HOFF + j] = (ushort)(__float_as_uint(lo) >> 16);
    }
    // key col k = tid
    float kv = fmaxf(p0[2048 + tid] + p1[2048 + tid] + biasN[2048 + tid], 0.f);
    if (t >= 1) Mk[((size_t)(t - 1) * BATCH + b) * KS + tid] = kv;
    if (t < 1 || t > 31) return;               // no attention read needed
    if (tid < t) wts[tid] = watt[(b * MM + t) * MM + tid];
    __syncthreads();
    red[tid] = hsh[tid] * W_g[tid] + hsh[tid + 256] * W_g[tid + 256];
    __syncthreads();
    for (int s = 128; s > 0; s >>= 1) {
        if (tid < s) red[tid] += red[tid + s];
        __syncthreads();
    }
    if (tid == 0) gsh = sigf(red[0] + b_g[0]);
    __syncthreads();
    float g = gsh;
    float acc = wts[t - 1] * kv;               // freshest Mk row from register
    for (int m = 0; m < t - 1; m++)
        acc += wts[m] * Mk[((size_t)m * BATCH + b) * KS + tid];
    float v = g * acc;
    uint u2 = __float_as_uint(v);
    rHi[tid] = (ushort)(u2 >> 16);
    float lo2 = v - __uint_as_float(u2 & 0xFFFF0000u);
    rLo[tid] = (ushort)(__float_as_uint(lo2) >> 16);
    if (tid == 0) {
        float vc = g * wc[b * MM + t];
        uint uc = __float_as_uint(vc);
        rHi[256] = (ushort)(uc >> 16);
        float lc = vc - __uint_as_float(uc & 0xFFFF0000u);
        rLo[256] = (ushort)(__float_as_uint(lc) >> 16);
    }
}

// ---------------------------------------------------------------------------
// Context norm over T, writes zero row t=32. (R0 form.)
// ---------------------------------------------------------------------------
__global__ void norm_k(float* __restrict__ z_pad, const float* __restrict__ gamma,
                       const float* __restrict__ beta)
{
    int b = blockIdx.x, zc = threadIdx.x;
    float* zb = z_pad + (size_t)b * (MM * ZS);
    float s = 0.f, s2 = 0.f;
    for (int t = 0; t < TT; t++) { float v = zb[t * ZS + zc]; s += v; s2 += v * v; }
    float mu = s * (1.f / 32.f);
    float var = s2 * (1.f / 32.f) - mu * mu;
    float rstd = 1.f / sqrtf(var + 1e-8f);
    float ga = gamma[zc], be = beta[zc];
    for (int t = 0; t < TT; t++) {
        float v = zb[t * ZS + zc];
        zb[t * ZS + zc] = (v - mu) * rstd * ga + be;
    }
    zb[TT * ZS + zc] = 0.f;
}

// ---------------------------------------------------------------------------
// Precompute attention weights + confidence sums (z-only, loop-invariant).
// ---------------------------------------------------------------------------
__global__ __launch_bounds__(256)
void scores_k(const float* __restrict__ z_pad, const float* __restrict__ cg_p,
              const float* __restrict__ cb_p, float* __restrict__ watt,
              float* __restrict__ wc)
{
    __shared__ float zs[MM * 129];
    int b = blockIdx.x, tid = threadIdx.x;
    const float* zb = z_pad + (size_t)b * (MM * ZS);
    for (int i = tid; i < MM * ZS; i += 256) {
        int m = i >> 7, k = i & 127;
        zs[m * 129 + k] = zb[i];
    }
    __syncthreads();
    float cg = cg_p[0], cb = cb_p[0];
    int wid = tid >> 6, lane = tid & 63;
    for (int t = 1 + wid; t <= 32; t += 4) {
        int m = lane;
        float s = -3.0e38f;
        if (m < t) {
            const float* zt = &zs[t * 129];
            const float* zm = &zs[m * 129];
            float acc = 0.f;
#pragma unroll 8
            for (int k = 0; k < ZS; k++) acc += zt[k] * zm[k];
            s = acc;
        }
        float mx = s;
        for (int off = 1; off < 64; off <<= 1) mx = fmaxf(mx, __shfl_xor(mx, off));
        float e = (m < t) ? expf(s - mx) : 0.f;
        float sum = e;
        for (int off = 1; off < 64; off <<= 1) sum += __shfl_xor(sum, off);
        float w = e / sum;
        if (m < t) watt[(b * MM + t) * MM + m] = w;
        float p = (m < t) ? w * sigf(s * cg + cb) : 0.f;
        for (int off = 1; off < 64; off <<= 1) p += __shfl_xor(p, off);
        if (lane == 0) wc[b * MM + t] = p;
    }
}

// ---------------------------------------------------------------------------
// Final y + argmax.
// ---------------------------------------------------------------------------
__global__ void y_k(const ushort* __restrict__ inpHi, const ushort* __restrict__ inpLo,
                    const float* __restrict__ W_y, const float* __restrict__ b_y,
                    float* __restrict__ out)
{
    int b = blockIdx.x, lane = threadIdx.x;
    const ushort* hHi = inpHi + (size_t)b * LDA + HOFF;
    const ushort* hLo = inpLo + (size_t)b * LDA + HOFF;
    float a0 = 0, a1 = 0, a2 = 0, a3 = 0;
    for (int r = 0; r < 8; r++) {
        int k = lane + r * 64;
        float hv = bf2f(hHi[k]) + bf2f(hLo[k]);
        a0 += hv * W_y[k];
        a1 += hv * W_y[512 + k];
        a2 += hv * W_y[1024 + k];
        a3 += hv * W_y[1536 + k];
    }
    for (int off = 32; off > 0; off >>= 1) {
        a0 += __shfl_xor(a0, off);
        a1 += __shfl_xor(a1, off);
        a2 += __shfl_xor(a2, off);
        a3 += __shfl_xor(a3, off);
    }
    if (lane == 0) {
        float y0 = a0 + b_y[0], y1 = a1 + b_y[1], y2 = a2 + b_y[2], y3 = a3 + b_y[3];
        out[b * 4 + 0] = y0; out[b * 4 + 1] = y1; out[b * 4 + 2] = y2; out[b * 4 + 3] = y3;
        int best = 0; float bv = y0;
        if (y1 > bv) { bv = y1; best = 1; }
        if (y2 > bv) { bv = y2; best = 2; }
        if (y3 > bv) { bv = y3; best = 3; }
        out[2048 + b] = (float)best;
    }
}

// ---------------------------------------------------------------------------
extern "C" void kernel_launch(void* const* d_in, const int* in_sizes, int n_in,
                              void* d_out, int out_size, void* d_ws, size_t ws_size,
                              hipStream_t stream)
{
    const float* x_seq = (const float*)d_in[0];
    const float* W_enc = (const float*)d_in[1];
    const float* gamma = (const float*)d_in[2];
    const float* beta  = (const float*)d_in[3];
    const float* W_ih  = (const float*)d_in[4];
    const float* W_hh  = (const float*)d_in[5];
    const float* b_ih  = (const float*)d_in[6];
    const float* b_hh  = (const float*)d_in[7];
    const float* W_key = (const float*)d_in[8];
    const float* b_key = (const float*)d_in[9];
    const float* W_g   = (const float*)d_in[10];
    const float* b_g   = (const float*)d_in[11];
    const float* cgain = (const float*)d_in[12];
    const float* cbias = (const float*)d_in[13];
    const float* W_y   = (const float*)d_in[14];
    const float* b_y   = (const float*)d_in[15];

    float* ws    = (float*)d_ws;
    float* z_pad = ws;                          // 2,162,688 f
    float* watt  = z_pad + 2162688;             // 557,568 f
    float* wcv   = watt + 557568;               // 16,896 f
    float* Mk    = wcv + 16896;                 // 4,194,304 f
    float* biasN = Mk + 4194304;                // 2,304 f
    float* cst   = biasN + 2304;                // 262,144 f
    ushort* inpHi0 = (ushort*)(cst + 262144);   // 409,600 us each
    ushort* inpLo0 = inpHi0 + 409600;
    ushort* inpHi1 = inpLo0 + 409600;
    ushort* inpLo1 = inpHi1 + 409600;
    ushort* Whi  = inpLo1 + 409600;             // 1,843,200 us
    ushort* Wlo  = Whi + NB * KPAD;             // 1,843,200 us
    ushort* Behi = Wlo + NB * KPAD;             // 131,072 us
    ushort* Belo = Behi + 131072;               // 131,072 us
    float* P0 = (float*)(Belo + 131072);        // 1,179,648 f (step K-split partials)
    float* P1 = P0 + (size_t)BATCH * NB;        // 1,179,648 f

    // zero c-state + all 4 input ping-pong buffers (contiguous region)
    hipMemsetAsync(cst, 0, 262144 * sizeof(float) + 4 * 409600 * sizeof(ushort), stream);

    prep_w<<<(NB * KPAD + 131072 + 255) / 256, 256, 0, stream>>>(
        W_ih, W_hh, W_key, b_ih, b_hh, b_key, W_enc, Whi, Wlo, Behi, Belo, biasN);

    // encoder: [16384 x 1024] @ [1024 x 128] -> z_pad (R0 form, single pass)
    gemm_mfma<128, 0, false><<<dim3(1, 512), 256, 0, stream>>>(
        x_seq, nullptr, nullptr, 1024, Behi, Belo, 1024, 32,
        z_pad, nullptr);
    norm_k<<<512, 128, 0, stream>>>(z_pad, gamma, beta);
    scores_k<<<512, 256, 0, stream>>>(z_pad, cgain, cbias, watt, wcv);

    for (int t = 0; t <= 32; t++) {
        ushort* inHiC = (t & 1) ? inpHi1 : inpHi0;
        ushort* inLoC = (t & 1) ? inpLo1 : inpLo0;
        ushort* inHiN = (t & 1) ? inpHi0 : inpHi1;
        ushort* inLoN = (t & 1) ? inpLo0 : inpLo1;
        gemm_mfma<64, 1, true><<<dim3(1152), 256, 0, stream>>>(
            nullptr, inHiC, inLoC, LDA, Whi, Wlo, KPAD, 25,
            P0, P1);
        cell_k<<<512, 256, 0, stream>>>(P0, P1, biasN, cst, inHiN, inLoN,
                                        Mk, W_g, b_g, watt, wcv, t);
    }
    y_k<<<512, 64, 0, stream>>>(inpHi1, inpLo1, W_y, b_y, (float*)d_out);
}

// Round 9
// 940.353 us; speedup vs baseline: 1.2831x; 1.0753x over previous
//
#include <hip/hip_runtime.h>
#include <math.h>

typedef unsigned short ushort;
typedef unsigned int uint;
typedef __bf16 bf16x8 __attribute__((ext_vector_type(8)));
typedef float f32x4 __attribute__((ext_vector_type(4)));

// Problem constants
#define ZS    128
#define KS    256
#define HS    512
#define BATCH 512
#define TT    32
#define MM    33
#define NB    2304      // 2048 gate cols (n = j*4+gate) + 256 key cols
#define KPAD  800       // 0..256 key_r, 257..271 zero pad, 272..783 h, 784..799 pad
#define HOFF  272
#define LDA   800

static __device__ __forceinline__ float sigf(float x) { return 1.f / (1.f + expf(-x)); }
static __device__ __forceinline__ float bf2f(ushort u) { return __uint_as_float((uint)u << 16); }

// ---------------------------------------------------------------------------
// Weight prep: Whi/Wlo [2304][800] bf16 (n-major, k-contig); Behi/Belo
// [128][1024] from W_enc transposed; biasN fused.
// ---------------------------------------------------------------------------
__global__ void prep_w(const float* __restrict__ W_ih, const float* __restrict__ W_hh,
                       const float* __restrict__ W_key, const float* __restrict__ b_ih,
                       const float* __restrict__ b_hh, const float* __restrict__ b_key,
                       const float* __restrict__ W_enc,
                       ushort* __restrict__ Whi, ushort* __restrict__ Wlo,
                       ushort* __restrict__ Behi, ushort* __restrict__ Belo,
                       float* __restrict__ biasN)
{
    int idx = blockIdx.x * 256 + threadIdx.x;
    if (idx < NB) {
        float bv;
        if (idx < 2048) { int j = idx >> 2, gi = idx & 3, r = gi * 512 + j; bv = b_ih[r] + b_hh[r]; }
        else bv = b_key[idx - 2048];
        biasN[idx] = bv;
    }
    if (idx < NB * KPAD) {
        int n = idx / KPAD, k = idx - n * KPAD;
        float v = 0.f;
        if (n < 2048) {
            int j = n >> 2, gi = n & 3, r = gi * 512 + j;
            if (k < 257) v = W_ih[r * 257 + k];
            else if (k >= HOFF && k < HOFF + 512) v = W_hh[r * 512 + (k - HOFF)];
        } else {
            if (k >= HOFF && k < HOFF + 512) v = W_key[(n - 2048) * 512 + (k - HOFF)];
        }
        uint u = __float_as_uint(v);
        Whi[idx] = (ushort)(u >> 16);
        float lo = v - __uint_as_float(u & 0xFFFF0000u);
        Wlo[idx] = (ushort)(__float_as_uint(lo) >> 16);
    } else if (idx < NB * KPAD + 128 * 1024) {
        int e = idx - NB * KPAD;
        int n = e >> 10, k = e & 1023;
        float v = W_enc[k * 128 + n];
        uint u = __float_as_uint(v);
        Behi[e] = (ushort)(u >> 16);
        float lo = v - __uint_as_float(u & 0xFFFF0000u);
        Belo[e] = (ushort)(__float_as_uint(lo) >> 16);
    }
}

// ---------------------------------------------------------------------------
// Encoder GEMM (R0 structure, proven): BM=32 x BN=128, fp32 A split on the
// fly, grid 512 (one block per 32 rows), nslice=32.
// ---------------------------------------------------------------------------
__global__ __launch_bounds__(256, 4)
void gemm_enc(const float* __restrict__ A,
              const ushort* __restrict__ Bhi, const ushort* __restrict__ Blo,
              float* __restrict__ out)
{
    constexpr int BN = 128, NI = 4;
    constexpr int AHI = 0, ALO = 32 * 40, BHI = 64 * 40, BLO = 64 * 40 + BN * 40;
    constexpr int BUF = 64 * 40 + 2 * BN * 40;
    __shared__ ushort lds[2 * BUF];
    const int tid = threadIdx.x;
    const int row0 = blockIdx.x * 32, n0 = 0;
    const int lda = 1024, ldb = 1024, nslice = 32;
    const int l = tid & 63, w = tid >> 6, wm = w >> 1, wn = w & 1;
    const int lm = l & 15, kg = (l >> 4) << 3;

    f32x4 acc[NI];
    const f32x4 zero4 = {0.f, 0.f, 0.f, 0.f};
#pragma unroll
    for (int ni = 0; ni < NI; ni++) acc[ni] = zero4;

    float4 avf;
    uint4 bhv[BN / 64], blv[BN / 64];

    auto LOADG = [&](int s) {
        const int k0 = s * 32;
        int r = tid >> 3, c = (tid & 7) << 2;
        avf = *(const float4*)(A + (size_t)(row0 + r) * lda + k0 + c);
#pragma unroll
        for (int i = 0; i < BN / 64; i++) {
            int idx = tid + 256 * i, r2 = idx >> 2, c2 = (idx & 3) << 3;
            bhv[i] = *(const uint4*)(Bhi + (size_t)(n0 + r2) * ldb + k0 + c2);
            blv[i] = *(const uint4*)(Blo + (size_t)(n0 + r2) * ldb + k0 + c2);
        }
    };
    auto STORE = [&](int buf) {
        ushort* L = lds + buf * BUF;
        int r = tid >> 3, c = (tid & 7) << 2;
        uint u0 = __float_as_uint(avf.x), u1 = __float_as_uint(avf.y);
        uint u2 = __float_as_uint(avf.z), u3 = __float_as_uint(avf.w);
        uint hp0 = (u1 & 0xFFFF0000u) | (u0 >> 16);
        uint hp1 = (u3 & 0xFFFF0000u) | (u2 >> 16);
        float l0 = avf.x - __uint_as_float(u0 & 0xFFFF0000u);
        float l1 = avf.y - __uint_as_float(u1 & 0xFFFF0000u);
        float l2 = avf.z - __uint_as_float(u2 & 0xFFFF0000u);
        float l3 = avf.w - __uint_as_float(u3 & 0xFFFF0000u);
        uint lp0 = (__float_as_uint(l1) & 0xFFFF0000u) | (__float_as_uint(l0) >> 16);
        uint lp1 = (__float_as_uint(l3) & 0xFFFF0000u) | (__float_as_uint(l2) >> 16);
        *(uint2*)&L[AHI + r * 40 + c] = make_uint2(hp0, hp1);
        *(uint2*)&L[ALO + r * 40 + c] = make_uint2(lp0, lp1);
#pragma unroll
        for (int i = 0; i < BN / 64; i++) {
            int idx = tid + 256 * i, r2 = idx >> 2, c2 = (idx & 3) << 3;
            *(uint4*)&L[BHI + r2 * 40 + c2] = bhv[i];
            *(uint4*)&L[BLO + r2 * 40 + c2] = blv[i];
        }
    };
    auto COMPUTE = [&](int buf) {
        const ushort* L = lds + buf * BUF;
        bf16x8 ah, alv, bh[NI], bl[NI];
        {
            int r = wm * 16 + lm;
            ah  = *(const bf16x8*)&L[AHI + r * 40 + kg];
            alv = *(const bf16x8*)&L[ALO + r * 40 + kg];
        }
#pragma unroll
        for (int ni = 0; ni < NI; ni++) {
            int r = wn * (BN / 2) + ni * 16 + lm;
            bh[ni] = *(const bf16x8*)&L[BHI + r * 40 + kg];
            bl[ni] = *(const bf16x8*)&L[BLO + r * 40 + kg];
        }
#pragma unroll
        for (int ni = 0; ni < NI; ni++) {
            acc[ni] = __builtin_amdgcn_mfma_f32_16x16x32_bf16(ah,  bh[ni], acc[ni], 0, 0, 0);
            acc[ni] = __builtin_amdgcn_mfma_f32_16x16x32_bf16(ah,  bl[ni], acc[ni], 0, 0, 0);
            acc[ni] = __builtin_amdgcn_mfma_f32_16x16x32_bf16(alv, bh[ni], acc[ni], 0, 0, 0);
        }
    };

    LOADG(0);
    STORE(0);
    for (int s = 0; s < nslice; s++) {
        if (s + 1 < nslice) LOADG(s + 1);
        __syncthreads();
        COMPUTE(s & 1);
        if (s + 1 < nslice) STORE((s + 1) & 1);
    }

    const int crow = (l >> 4) << 2;   // C/D: row = (lane>>4)*4 + reg, col = lane&15
#pragma unroll
    for (int ni = 0; ni < NI; ni++)
#pragma unroll
        for (int r = 0; r < 4; r++) {
            int m = row0 + wm * 16 + crow + r;
            int z = n0 + wn * (BN / 2) + ni * 16 + lm;
            out[(size_t)(m >> 5) * (MM * ZS) + (m & 31) * ZS + z] = acc[ni][r];
        }
}

// ---------------------------------------------------------------------------
// Step GEMM — LDS-traffic-optimized tile (R8 post-mortem: step GEMM is
// LDS-read-throughput-bound, per-CU shared, so occupancy didn't help).
// BM=64 x BN=64, 4 waves in 2x2, each wave owns a 32x32 output tile
// (2x2 16x16 subtiles): per K=32 slice a wave issues 8 ds_read_b128 feeding
// 12 MFMAs (0.67 reads/MFMA vs 1.0 before), and staged bytes per output
// halve. K-SPLIT z=2 (slices 0..12 / 13..24), flat grid 576 = 8 XCDs * 72
// XCD-contiguous swizzle (weights L2-resident). Same proven sync structure
// as R0: LOADG -> __syncthreads -> COMPUTE -> STORE.
// ---------------------------------------------------------------------------
__global__ __launch_bounds__(256, 4)
void gemm_step(const ushort* __restrict__ Ahi, const ushort* __restrict__ Alo,
               const ushort* __restrict__ Whi, const ushort* __restrict__ Wlo,
               float* __restrict__ P0, float* __restrict__ P1)
{
    constexpr int AHI = 0, ALO = 64 * 40, BHI = 128 * 40, BLO = 192 * 40;
    constexpr int BUF = 256 * 40;          // 10240 ushorts = 20KB per buffer
    __shared__ ushort lds[2 * BUF];
    const int tid = threadIdx.x;
    int wg = blockIdx.x;
    int swz = (wg & 7) * 72 + (wg >> 3);   // 576 = 8 XCDs * 72, bijective
    int zz = swz / 288;
    int rr = swz - zz * 288;
    const int bx = rr >> 3, by = rr & 7;   // bx 0..35 (N tiles), by 0..7 (M tiles)
    const int kb = zz ? 13 : 0, kc = zz ? 12 : 13;
    float* __restrict__ out = zz ? P1 : P0;
    const int row0 = by * 64, n0 = bx * 64;
    const int l = tid & 63, w = tid >> 6, wm = w >> 1, wn = w & 1;
    const int lm = l & 15, kg = (l >> 4) << 3;
    const int ar = tid >> 2, ac = (tid & 3) << 3;   // staging row/col (64 rows x 4 uint4)

    f32x4 acc[2][2];
    const f32x4 zero4 = {0.f, 0.f, 0.f, 0.f};
    acc[0][0] = zero4; acc[0][1] = zero4; acc[1][0] = zero4; acc[1][1] = zero4;

    uint4 av0, av1, bv0, bv1;

    auto LOADG = [&](int a) {
        const int k0 = a * 32;
        av0 = *(const uint4*)(Ahi + (size_t)(row0 + ar) * LDA + k0 + ac);
        av1 = *(const uint4*)(Alo + (size_t)(row0 + ar) * LDA + k0 + ac);
        bv0 = *(const uint4*)(Whi + (size_t)(n0 + ar) * KPAD + k0 + ac);
        bv1 = *(const uint4*)(Wlo + (size_t)(n0 + ar) * KPAD + k0 + ac);
    };
    auto STORE = [&](int buf) {
        ushort* L = lds + buf * BUF;
        int off = ar * 40 + ac;
        *(uint4*)&L[AHI + off] = av0;
        *(uint4*)&L[ALO + off] = av1;
        *(uint4*)&L[BHI + off] = bv0;
        *(uint4*)&L[BLO + off] = bv1;
    };
    auto COMPUTE = [&](int buf) {
        const ushort* L = lds + buf * BUF;
        bf16x8 ah[2], al[2], bh[2], bl[2];
#pragma unroll
        for (int mi = 0; mi < 2; mi++) {
            int r = wm * 32 + mi * 16 + lm;
            ah[mi] = *(const bf16x8*)&L[AHI + r * 40 + kg];
            al[mi] = *(const bf16x8*)&L[ALO + r * 40 + kg];
        }
#pragma unroll
        for (int ni = 0; ni < 2; ni++) {
            int r = wn * 32 + ni * 16 + lm;
            bh[ni] = *(const bf16x8*)&L[BHI + r * 40 + kg];
            bl[ni] = *(const bf16x8*)&L[BLO + r * 40 + kg];
        }
#pragma unroll
        for (int mi = 0; mi < 2; mi++)
#pragma unroll
            for (int ni = 0; ni < 2; ni++) {
                acc[mi][ni] = __builtin_amdgcn_mfma_f32_16x16x32_bf16(ah[mi], bh[ni], acc[mi][ni], 0, 0, 0);
                acc[mi][ni] = __builtin_amdgcn_mfma_f32_16x16x32_bf16(ah[mi], bl[ni], acc[mi][ni], 0, 0, 0);
                acc[mi][ni] = __builtin_amdgcn_mfma_f32_16x16x32_bf16(al[mi], bh[ni], acc[mi][ni], 0, 0, 0);
            }
    };

    LOADG(kb);
    STORE(0);
    for (int s = 0; s < kc; s++) {
        if (s + 1 < kc) LOADG(kb + s + 1);
        __syncthreads();
        COMPUTE(s & 1);
        if (s + 1 < kc) STORE((s + 1) & 1);
    }

    const int crow = (l >> 4) << 2;   // C/D: row = (lane>>4)*4 + reg, col = lane&15
#pragma unroll
    for (int mi = 0; mi < 2; mi++)
#pragma unroll
        for (int ni = 0; ni < 2; ni++)
#pragma unroll
            for (int r = 0; r < 4; r++) {
                int b = row0 + wm * 32 + mi * 16 + crow + r;
                int n = n0 + wn * 32 + ni * 16 + lm;
                out[(size_t)b * NB + n] = acc[mi][ni][r];
            }
}

// ---------------------------------------------------------------------------
// Fused per-step cell: sums K-split partials, bias, LSTM cell, h write
// (bf16 hi/lo), key relu -> Mk, then g-gate + attention read -> key_r(t+1).
// One block per batch row. Mk row t-1 consumed from register.
// ---------------------------------------------------------------------------
__global__ __launch_bounds__(256)
void cell_k(const float* __restrict__ P0, const float* __restrict__ P1,
            const float* __restrict__ biasN, float* __restrict__ cst,
            ushort* __restrict__ outHi, ushort* __restrict__ outLo,
            float* __restrict__ Mk,
            const float* __restrict__ W_g, const float* __restrict__ b_g,
            const float* __restrict__ watt, const float* __restrict__ wc,
            int t)
{
    __shared__ float hsh[512];
    __shared__ float red[256];
    __shared__ float wts[32];
    __shared__ float gsh;
    int b = blockIdx.x, tid = threadIdx.x;
    const float* p0 = P0 + (size_t)b * NB;
    const float* p1 = P1 + (size_t)b * NB;
    ushort* rHi = outHi + (size_t)b * LDA;
    ushort* rLo = outLo + (size_t)b * LDA;
#pragma unroll
    for (int u = 0; u < 2; u++) {
        int j = tid + u * 256;                 // hidden unit
        float4 a  = *(const float4*)(p0 + 4 * j);
        float4 c4 = *(const float4*)(p1 + 4 * j);
        float4 bb = *(const float4*)(biasN + 4 * j);
        float gi = a.x + c4.x + bb.x;          // PyTorch gate order i,f,g,o
        float gf = a.y + c4.y + bb.y;
        float gg = a.z + c4.z + bb.z;
        float go = a.w + c4.w + bb.w;
        float iv = sigf(gi), fv = sigf(gf), gv = tanhf(gg), ov = sigf(go);
        float cn = fv * cst[(size_t)b * HS + j] + iv * gv;
        float hv = ov * tanhf(cn);
        cst[(size_t)b * HS + j] = cn;
        hsh[j] = hv;
        uint uu = __float_as_uint(hv);
        rHi[HOFF + j] = (ushort)(uu >> 16);
        float lo = hv - __uint_as_float(uu & 0xFFFF0000u);
        rLo[HOFF + j] = (ushort)(__float_as_uint(lo) >> 16);
    }
    // key col k = tid
    float kv = fmaxf(p0[2048 + tid] + p1[2048 + tid] + biasN[2048 + tid], 0.f);
    if (t >= 1) Mk[((size_t)(t - 1) * BATCH + b) * KS + tid] = kv;
    if (t < 1 || t > 31) return;               // no attention read needed
    if (tid < t) wts[tid] = watt[(b * MM + t) * MM + tid];
    __syncthreads();
    red[tid] = hsh[tid] * W_g[tid] + hsh[tid + 256] * W_g[tid + 256];
    __syncthreads();
    for (int s = 128; s > 0; s >>= 1) {
        if (tid < s) red[tid] += red[tid + s];
        __syncthreads();
    }
    if (tid == 0) gsh = sigf(red[0] + b_g[0]);
    __syncthreads();
    float g = gsh;
    float acc = wts[t - 1] * kv;               // freshest Mk row from register
    for (int m = 0; m < t - 1; m++)
        acc += wts[m] * Mk[((size_t)m * BATCH + b) * KS + tid];
    float v = g * acc;
    uint u2 = __float_as_uint(v);
    rHi[tid] = (ushort)(u2 >> 16);
    float lo2 = v - __uint_as_float(u2 & 0xFFFF0000u);
    rLo[tid] = (ushort)(__float_as_uint(lo2) >> 16);
    if (tid == 0) {
        float vc = g * wc[b * MM + t];
        uint uc = __float_as_uint(vc);
        rHi[256] = (ushort)(uc >> 16);
        float lc = vc - __uint_as_float(uc & 0xFFFF0000u);
        rLo[256] = (ushort)(__float_as_uint(lc) >> 16);
    }
}

// ---------------------------------------------------------------------------
// Context norm over T, writes zero row t=32. (R0 form.)
// ---------------------------------------------------------------------------
__global__ void norm_k(float* __restrict__ z_pad, const float* __restrict__ gamma,
                       const float* __restrict__ beta)
{
    int b = blockIdx.x, zc = threadIdx.x;
    float* zb = z_pad + (size_t)b * (MM * ZS);
    float s = 0.f, s2 = 0.f;
    for (int t = 0; t < TT; t++) { float v = zb[t * ZS + zc]; s += v; s2 += v * v; }
    float mu = s * (1.f / 32.f);
    float var = s2 * (1.f / 32.f) - mu * mu;
    float rstd = 1.f / sqrtf(var + 1e-8f);
    float ga = gamma[zc], be = beta[zc];
    for (int t = 0; t < TT; t++) {
        float v = zb[t * ZS + zc];
        zb[t * ZS + zc] = (v - mu) * rstd * ga + be;
    }
    zb[TT * ZS + zc] = 0.f;
}

// ---------------------------------------------------------------------------
// Precompute attention weights + confidence sums (z-only, loop-invariant).
// ---------------------------------------------------------------------------
__global__ __launch_bounds__(256)
void scores_k(const float* __restrict__ z_pad, const float* __restrict__ cg_p,
              const float* __restrict__ cb_p, float* __restrict__ watt,
              float* __restrict__ wc)
{
    __shared__ float zs[MM * 129];
    int b = blockIdx.x, tid = threadIdx.x;
    const float* zb = z_pad + (size_t)b * (MM * ZS);
    for (int i = tid; i < MM * ZS; i += 256) {
        int m = i >> 7, k = i & 127;
        zs[m * 129 + k] = zb[i];
    }
    __syncthreads();
    float cg = cg_p[0], cb = cb_p[0];
    int wid = tid >> 6, lane = tid & 63;
    for (int t = 1 + wid; t <= 32; t += 4) {
        int m = lane;
        float s = -3.0e38f;
        if (m < t) {
            const float* zt = &zs[t * 129];
            const float* zm = &zs[m * 129];
            float acc = 0.f;
#pragma unroll 8
            for (int k = 0; k < ZS; k++) acc += zt[k] * zm[k];
            s = acc;
        }
        float mx = s;
        for (int off = 1; off < 64; off <<= 1) mx = fmaxf(mx, __shfl_xor(mx, off));
        float e = (m < t) ? expf(s - mx) : 0.f;
        float sum = e;
        for (int off = 1; off < 64; off <<= 1) sum += __shfl_xor(sum, off);
        float w = e / sum;
        if (m < t) watt[(b * MM + t) * MM + m] = w;
        float p = (m < t) ? w * sigf(s * cg + cb) : 0.f;
        for (int off = 1; off < 64; off <<= 1) p += __shfl_xor(p, off);
        if (lane == 0) wc[b * MM + t] = p;
    }
}

// ---------------------------------------------------------------------------
// Final y + argmax.
// ---------------------------------------------------------------------------
__global__ void y_k(const ushort* __restrict__ inpHi, const ushort* __restrict__ inpLo,
                    const float* __restrict__ W_y, const float* __restrict__ b_y,
                    float* __restrict__ out)
{
    int b = blockIdx.x, lane = threadIdx.x;
    const ushort* hHi = inpHi + (size_t)b * LDA + HOFF;
    const ushort* hLo = inpLo + (size_t)b * LDA + HOFF;
    float a0 = 0, a1 = 0, a2 = 0, a3 = 0;
    for (int r = 0; r < 8; r++) {
        int k = lane + r * 64;
        float hv = bf2f(hHi[k]) + bf2f(hLo[k]);
        a0 += hv * W_y[k];
        a1 += hv * W_y[512 + k];
        a2 += hv * W_y[1024 + k];
        a3 += hv * W_y[1536 + k];
    }
    for (int off = 32; off > 0; off >>= 1) {
        a0 += __shfl_xor(a0, off);
        a1 += __shfl_xor(a1, off);
        a2 += __shfl_xor(a2, off);
        a3 += __shfl_xor(a3, off);
    }
    if (lane == 0) {
        float y0 = a0 + b_y[0], y1 = a1 + b_y[1], y2 = a2 + b_y[2], y3 = a3 + b_y[3];
        out[b * 4 + 0] = y0; out[b * 4 + 1] = y1; out[b * 4 + 2] = y2; out[b * 4 + 3] = y3;
        int best = 0; float bv = y0;
        if (y1 > bv) { bv = y1; best = 1; }
        if (y2 > bv) { bv = y2; best = 2; }
        if (y3 > bv) { bv = y3; best = 3; }
        out[2048 + b] = (float)best;
    }
}

// ---------------------------------------------------------------------------
extern "C" void kernel_launch(void* const* d_in, const int* in_sizes, int n_in,
                              void* d_out, int out_size, void* d_ws, size_t ws_size,
                              hipStream_t stream)
{
    const float* x_seq = (const float*)d_in[0];
    const float* W_enc = (const float*)d_in[1];
    const float* gamma = (const float*)d_in[2];
    const float* beta  = (const float*)d_in[3];
    const float* W_ih  = (const float*)d_in[4];
    const float* W_hh  = (const float*)d_in[5];
    const float* b_ih  = (const float*)d_in[6];
    const float* b_hh  = (const float*)d_in[7];
    const float* W_key = (const float*)d_in[8];
    const float* b_key = (const float*)d_in[9];
    const float* W_g   = (const float*)d_in[10];
    const float* b_g   = (const float*)d_in[11];
    const float* cgain = (const float*)d_in[12];
    const float* cbias = (const float*)d_in[13];
    const float* W_y   = (const float*)d_in[14];
    const float* b_y   = (const float*)d_in[15];

    float* ws    = (float*)d_ws;
    float* z_pad = ws;                          // 2,162,688 f
    float* watt  = z_pad + 2162688;             // 557,568 f
    float* wcv   = watt + 557568;               // 16,896 f
    float* Mk    = wcv + 16896;                 // 4,194,304 f
    float* biasN = Mk + 4194304;                // 2,304 f
    float* cst   = biasN + 2304;                // 262,144 f
    ushort* inpHi0 = (ushort*)(cst + 262144);   // 409,600 us each
    ushort* inpLo0 = inpHi0 + 409600;
    ushort* inpHi1 = inpLo0 + 409600;
    ushort* inpLo1 = inpHi1 + 409600;
    ushort* Whi  = inpLo1 + 409600;             // 1,843,200 us
    ushort* Wlo  = Whi + NB * KPAD;             // 1,843,200 us
    ushort* Behi = Wlo + NB * KPAD;             // 131,072 us
    ushort* Belo = Behi + 131072;               // 131,072 us
    float* P0 = (float*)(Belo + 131072);        // 1,179,648 f (step K-split partials)
    float* P1 = P0 + (size_t)BATCH * NB;        // 1,179,648 f

    // zero c-state + all 4 input ping-pong buffers (contiguous region)
    hipMemsetAsync(cst, 0, 262144 * sizeof(float) + 4 * 409600 * sizeof(ushort), stream);

    prep_w<<<(NB * KPAD + 131072 + 255) / 256, 256, 0, stream>>>(
        W_ih, W_hh, W_key, b_ih, b_hh, b_key, W_enc, Whi, Wlo, Behi, Belo, biasN);

    // encoder: [16384 x 1024] @ [1024 x 128] -> z_pad (R0 form)
    gemm_enc<<<512, 256, 0, stream>>>(x_seq, Behi, Belo, z_pad);
    norm_k<<<512, 128, 0, stream>>>(z_pad, gamma, beta);
    scores_k<<<512, 256, 0, stream>>>(z_pad, cgain, cbias, watt, wcv);

    for (int t = 0; t <= 32; t++) {
        ushort* inHiC = (t & 1) ? inpHi1 : inpHi0;
        ushort* inLoC = (t & 1) ? inpLo1 : inpLo0;
        ushort* inHiN = (t & 1) ? inpHi0 : inpHi1;
        ushort* inLoN = (t & 1) ? inpLo0 : inpLo1;
        gemm_step<<<576, 256, 0, stream>>>(inHiC, inLoC, Whi, Wlo, P0, P1);
        cell_k<<<512, 256, 0, stream>>>(P0, P1, biasN, cst, inHiN, inLoN,
                                        Mk, W_g, b_g, watt, wcv, t);
    }
    y_k<<<512, 64, 0, stream>>>(inpHi1, inpLo1, W_y, b_y, (float*)d_out);
}